// Round 5
// baseline (294.989 us; speedup 1.0000x reference)
//
#include <hip/hip_runtime.h>
#include <hip/hip_bf16.h>
#include <math.h>

#define B__ 64
#define NTOK 512
#define CDIM 192
#define HEADS 6
#define HD 32
#define NW 16
#define T3 3375
#define HID 512
#define LOG2E 1.4426950408889634f

typedef _Float16 f16x8 __attribute__((ext_vector_type(8)));
typedef _Float16 f16x4 __attribute__((ext_vector_type(4)));
typedef float    f32x4 __attribute__((ext_vector_type(4)));

#if __has_builtin(__builtin_amdgcn_exp2f)
#define EXP2F(x) __builtin_amdgcn_exp2f(x)
#else
#define EXP2F(x) __expf(0.69314718056f*(x))
#endif

// ---------------- K1: CPB MLP -> tbl_t[6][3375] (16*sigmoid applied) ----------------
__global__ __launch_bounds__(512) void k_cpb(
    const float* __restrict__ rel_table, const float* __restrict__ w1,
    const float* __restrict__ b1, const float* __restrict__ w2,
    float* __restrict__ tbl_t) {
  int i = blockIdx.x;          // table row 0..3374
  int t = threadIdx.x;         // hidden unit 0..511
  float t0 = rel_table[i*3+0], t1 = rel_table[i*3+1], t2 = rel_table[i*3+2];
  float hval = fmaxf(t0*w1[t*3+0] + t1*w1[t*3+1] + t2*w1[t*3+2] + b1[t], 0.f);
  __shared__ float red[8][6];
  int wv = t >> 6, lane = t & 63;
  #pragma unroll
  for (int hh = 0; hh < 6; ++hh) {
    float p = hval * w2[hh*HID + t];
    #pragma unroll
    for (int off = 32; off > 0; off >>= 1) p += __shfl_down(p, off);
    if (lane == 0) red[wv][hh] = p;
  }
  __syncthreads();
  if (t < 6) {
    float s = 0.f;
    #pragma unroll
    for (int w8 = 0; w8 < 8; ++w8) s += red[w8][t];
    tbl_t[t*T3 + i] = 16.f / (1.f + __expf(-s));
  }
}

// ---------------- K2: combined (bias+mask)*log2e -> swapped-S fragment layout, fp16 ----
// Fragment element (lane l, reg r): k = kt*16 + (l>>4)*4 + r (C row), q = qt*16 + (l&15) (C col)
__global__ __launch_bounds__(64) void k_bm(
    const int* __restrict__ idx, const float* __restrict__ tbl_t,
    const float* __restrict__ mask, _Float16* __restrict__ bm) {
  int bx = blockIdx.x;              // qt*32+kt
  int hw = blockIdx.y;              // h*16+w
  int h = hw >> 4, w = hw & 15;
  int l = threadIdx.x;
  int qt = bx >> 5, kt = bx & 31;
  int q  = qt*16 + (l & 15);
  int k0 = kt*16 + (l >> 4)*4;
  const float* mp = mask + (size_t)w*262144 + (size_t)q*512 + k0;
  const int*   ip = idx + (size_t)q*512 + k0;
  const float* tb = tbl_t + (size_t)h*T3;
  f16x4 v;
  #pragma unroll
  for (int r = 0; r < 4; ++r)
    v[r] = (_Float16)(LOG2E * (tb[ip[r]] + mp[r]));
  *(f16x4*)(bm + ((size_t)hw*1024 + bx)*256 + l*4) = v;
}

// ---------------- K3a: x fp32 -> fp16 ----------------
__global__ __launch_bounds__(256) void k_xh(
    const float* __restrict__ x, _Float16* __restrict__ xh) {
  int i = blockIdx.x*256 + threadIdx.x;     // 6144*256 = 1572864 float4 exactly
  float4 v = ((const float4*)x)[i];
  f16x4 h = {(_Float16)v.x, (_Float16)v.y, (_Float16)v.z, (_Float16)v.w};
  *(f16x4*)(xh + (size_t)i*4) = h;
}

// ---------------- K3b: weights fp32 -> fp16 (qkv_w then proj_w, contiguous) ----------------
__global__ __launch_bounds__(256) void k_wh(
    const float* __restrict__ qkv_w, const float* __restrict__ proj_w,
    _Float16* __restrict__ wh) {
  int i = blockIdx.x*256 + threadIdx.x;     // 144*256 = 36864 float4 exactly
  float4 v = (i < 27648) ? ((const float4*)qkv_w)[i] : ((const float4*)proj_w)[i - 27648];
  f16x4 h = {(_Float16)v.x, (_Float16)v.y, (_Float16)v.z, (_Float16)v.w};
  *(f16x4*)(wh + (size_t)i*4) = h;
}

// ---------------- K4: QKV GEMM via MFMA + bias + q/k row-norm + logit scale ----------------
// xh:[32768][192] fp16, wh(qkv):[576][192] fp16
// qn/kn: [B*H][N][HD] fp16 (qn pre-scaled by exp(ls)*log2e); v stored TRANSPOSED to vt[B*H][HD][N]
__global__ __launch_bounds__(256) void k_qkv(
    const _Float16* __restrict__ xh, const _Float16* __restrict__ wh,
    const float* __restrict__ q_bias, const float* __restrict__ v_bias,
    const float* __restrict__ logit_scale,
    _Float16* __restrict__ qn, _Float16* __restrict__ kn, _Float16* __restrict__ vt) {
  int wid = threadIdx.x >> 6, l = threadIdx.x & 63;
  int lr = l & 15, lg = l >> 4;
  int m0 = blockIdx.x*128 + wid*32;
  int cb = blockIdx.y;
  int c0 = cb*64;
  int p  = cb/3;                    // 0=q 1=k 2=v
  int pc0 = (cb - p*3)*64;          // col offset within part
  int h0 = pc0 >> 5;                // first head of this tile

  const f32x4 zero = {0.f,0.f,0.f,0.f};
  f32x4 acc[2][4];
  #pragma unroll
  for (int mt = 0; mt < 2; ++mt)
    #pragma unroll
    for (int nt = 0; nt < 4; ++nt) acc[mt][nt] = zero;

  const _Float16* wb = wh + (size_t)c0*192;
  for (int kc = 0; kc < 6; ++kc) {
    int ko = kc*32 + lg*8;
    f16x8 a0 = *(const f16x8*)(xh + (size_t)(m0 + lr)*192 + ko);
    f16x8 a1 = *(const f16x8*)(xh + (size_t)(m0 + 16 + lr)*192 + ko);
    #pragma unroll
    for (int nt = 0; nt < 4; ++nt) {
      f16x8 bf = *(const f16x8*)(wb + (size_t)(nt*16 + lr)*192 + ko);
      acc[0][nt] = __builtin_amdgcn_mfma_f32_16x16x32_f16(a0, bf, acc[0][nt], 0, 0, 0);
      acc[1][nt] = __builtin_amdgcn_mfma_f32_16x16x32_f16(a1, bf, acc[1][nt], 0, 0, 0);
    }
  }

  // epilogue: C row = m0 + mt*16 + lg*4 + r, col = nt*16 + lr
  if (p == 0) {
    float bq[4];
    #pragma unroll
    for (int nt = 0; nt < 4; ++nt) bq[nt] = q_bias[pc0 + nt*16 + lr];
    float s0 = __expf(fminf(logit_scale[h0], 4.6051702f)) * LOG2E;
    float s1 = __expf(fminf(logit_scale[h0+1], 4.6051702f)) * LOG2E;
    #pragma unroll
    for (int mt = 0; mt < 2; ++mt) {
      #pragma unroll
      for (int nt = 0; nt < 4; ++nt)
        #pragma unroll
        for (int r = 0; r < 4; ++r) acc[mt][nt][r] += bq[nt];
      #pragma unroll
      for (int r = 0; r < 4; ++r) {
        float ss0 = acc[mt][0][r]*acc[mt][0][r] + acc[mt][1][r]*acc[mt][1][r];
        float ss1 = acc[mt][2][r]*acc[mt][2][r] + acc[mt][3][r]*acc[mt][3][r];
        #pragma unroll
        for (int off = 1; off < 16; off <<= 1) {
          ss0 += __shfl_xor(ss0, off);
          ss1 += __shfl_xor(ss1, off);
        }
        float inv0 = s0 / fmaxf(sqrtf(ss0), 1e-12f);
        float inv1 = s1 / fmaxf(sqrtf(ss1), 1e-12f);
        int m = m0 + mt*16 + lg*4 + r;
        int b = m >> 9, n = m & 511;
        #pragma unroll
        for (int nt = 0; nt < 4; ++nt) {
          int h = h0 + (nt >> 1);
          int d = (nt & 1)*16 + lr;
          float val = acc[mt][nt][r] * ((nt < 2) ? inv0 : inv1);
          qn[(((size_t)b*HEADS + h)*NTOK + n)*HD + d] = (_Float16)val;
        }
      }
    }
  } else if (p == 1) {
    #pragma unroll
    for (int mt = 0; mt < 2; ++mt) {
      #pragma unroll
      for (int r = 0; r < 4; ++r) {
        float ss0 = acc[mt][0][r]*acc[mt][0][r] + acc[mt][1][r]*acc[mt][1][r];
        float ss1 = acc[mt][2][r]*acc[mt][2][r] + acc[mt][3][r]*acc[mt][3][r];
        #pragma unroll
        for (int off = 1; off < 16; off <<= 1) {
          ss0 += __shfl_xor(ss0, off);
          ss1 += __shfl_xor(ss1, off);
        }
        float inv0 = 1.f / fmaxf(sqrtf(ss0), 1e-12f);
        float inv1 = 1.f / fmaxf(sqrtf(ss1), 1e-12f);
        int m = m0 + mt*16 + lg*4 + r;
        int b = m >> 9, n = m & 511;
        #pragma unroll
        for (int nt = 0; nt < 4; ++nt) {
          int h = h0 + (nt >> 1);
          int d = (nt & 1)*16 + lr;
          float val = acc[mt][nt][r] * ((nt < 2) ? inv0 : inv1);
          kn[(((size_t)b*HEADS + h)*NTOK + n)*HD + d] = (_Float16)val;
        }
      }
    }
  } else {
    // V: store transposed vt[pair][d][n]; r indexes consecutive n -> packed f16x4 store
    float bv[4];
    #pragma unroll
    for (int nt = 0; nt < 4; ++nt) bv[nt] = v_bias[pc0 + nt*16 + lr];
    #pragma unroll
    for (int mt = 0; mt < 2; ++mt) {
      int m = m0 + mt*16 + lg*4;
      int b = m >> 9, n = m & 511;
      #pragma unroll
      for (int nt = 0; nt < 4; ++nt) {
        int h = h0 + (nt >> 1);
        int d = (nt & 1)*16 + lr;
        f16x4 hv;
        #pragma unroll
        for (int r = 0; r < 4; ++r) hv[r] = (_Float16)(acc[mt][nt][r] + bv[nt]);
        *(f16x4*)(vt + (((size_t)b*HEADS + h)*HD + d)*NTOK + n) = hv;
      }
    }
  }
}

// ---------------- K5: MFMA flash attention (swapped-S, bm via MFMA C operand) ----------------
// grid (4 qblk, 6 h, 64 b), 256 thr = 4 waves, wave owns 32 q rows
__global__ __launch_bounds__(256) void k_attn(
    const _Float16* __restrict__ qn, const _Float16* __restrict__ kn,
    const _Float16* __restrict__ vt, const _Float16* __restrict__ bm,
    _Float16* __restrict__ ao_h) {
  __shared__ _Float16 plds[4][32][88];
  int qblk = blockIdx.x, h = blockIdx.y, b = blockIdx.z;
  int w = b & (NW-1);
  int wid = threadIdx.x >> 6, l = threadIdx.x & 63;
  int lr = l & 15, lg = l >> 4;
  size_t pair = (size_t)b*HEADS + h;
  const _Float16* qb = qn + pair*NTOK*HD;
  const _Float16* kb = kn + pair*NTOK*HD;
  const _Float16* vb = vt + pair*HD*NTOK;
  const _Float16* bm_base = bm + ((size_t)(h*16 + w)*1024)*256;
  int q0 = qblk*128 + wid*32;
  int qtb = q0 >> 4;

  // Q = B-operand fragment: lane lr = q-col, lg = d-octet
  f16x8 aq[2];
  aq[0] = *(const f16x8*)(qb + (size_t)(q0 + lr)*HD + lg*8);
  aq[1] = *(const f16x8*)(qb + (size_t)(q0 + 16 + lr)*HD + lg*8);

  const f32x4 zero = {0.f, 0.f, 0.f, 0.f};
  f32x4 o[2][2];
  o[0][0] = zero; o[0][1] = zero; o[1][0] = zero; o[1][1] = zero;
  float mrun[2] = {-1e30f, -1e30f};
  float lrun[2] = {0.f, 0.f};

  for (int ch = 0; ch < 8; ++ch) {
    // K = A-operand fragments
    f16x8 bk[4];
    #pragma unroll
    for (int kt = 0; kt < 4; ++kt)
      bk[kt] = *(const f16x8*)(kb + (size_t)(ch*64 + kt*16 + lr)*HD + lg*8);
    // S^T = K Q + (bias+mask)*log2e   (C row=(lg,r)=k, col=lr=q)
    f32x4 s[2][4];
    #pragma unroll
    for (int mt = 0; mt < 2; ++mt) {
      #pragma unroll
      for (int kt = 0; kt < 4; ++kt) {
        size_t toff = ((size_t)((qtb + mt)*32 + ch*4 + kt))*256 + l*4;
        f16x4 c4 = *(const f16x4*)(bm_base + toff);
        f32x4 cf = {(float)c4[0], (float)c4[1], (float)c4[2], (float)c4[3]};
        s[mt][kt] = __builtin_amdgcn_mfma_f32_16x16x32_f16(bk[kt], aq[mt], cf, 0, 0, 0);
      }
    }
    // online softmax in log2 domain; stats live at q = lr lanes
    #pragma unroll
    for (int mt = 0; mt < 2; ++mt) {
      float pm = s[mt][0][0];
      #pragma unroll
      for (int kt = 0; kt < 4; ++kt)
        #pragma unroll
        for (int r = 0; r < 4; ++r) pm = fmaxf(pm, s[mt][kt][r]);
      pm = fmaxf(pm, __shfl_xor(pm, 16));
      pm = fmaxf(pm, __shfl_xor(pm, 32));
      // defer-max (T13): skip rescale while tile max within 8 (log2) of running max
      if (!__all(pm <= mrun[mt] + 8.f)) {
        float mnew = fmaxf(mrun[mt], pm);
        float corr = EXP2F(mrun[mt] - mnew);
        lrun[mt] *= corr;
        mrun[mt] = mnew;
        // redistribute corr from lr-lanes to (lg,r)-lanes for O rescale
        #pragma unroll
        for (int r = 0; r < 4; ++r) {
          float cr = __shfl(corr, (l >> 4)*4 + r);
          o[mt][0][r] *= cr;
          o[mt][1][r] *= cr;
        }
      }
      float mref = mrun[mt];
      float rs = 0.f;
      #pragma unroll
      for (int kt = 0; kt < 4; ++kt) {
        f16x4 pv;
        #pragma unroll
        for (int r = 0; r < 4; ++r) {
          float p = EXP2F(s[mt][kt][r] - mref);
          pv[r] = (_Float16)p;
          rs += p;
        }
        *(f16x4*)(&plds[wid][mt*16 + lr][kt*16 + lg*4]) = pv;
      }
      rs += __shfl_xor(rs, 16);
      rs += __shfl_xor(rs, 32);
      lrun[mt] += rs;
    }
    // O += P V  (A=P rows=q, B=V cols=d; C row=(lg,r)=q, col=lr=d)
    #pragma unroll
    for (int kk = 0; kk < 2; ++kk) {
      f16x8 ap0 = *(const f16x8*)(&plds[wid][lr][kk*32 + lg*8]);
      f16x8 ap1 = *(const f16x8*)(&plds[wid][16 + lr][kk*32 + lg*8]);
      #pragma unroll
      for (int dt = 0; dt < 2; ++dt) {
        f16x8 bv = *(const f16x8*)(vb + (size_t)(dt*16 + lr)*NTOK + ch*64 + kk*32 + lg*8);
        o[0][dt] = __builtin_amdgcn_mfma_f32_16x16x32_f16(ap0, bv, o[0][dt], 0, 0, 0);
        o[1][dt] = __builtin_amdgcn_mfma_f32_16x16x32_f16(ap1, bv, o[1][dt], 0, 0, 0);
      }
    }
  }
  // epilogue: 1/l lives at lr-lanes; redistribute to (lg,r), store fp16
  _Float16* op = ao_h + (size_t)b*NTOK*CDIM + (size_t)h*HD;
  #pragma unroll
  for (int mt = 0; mt < 2; ++mt) {
    float inv = 1.f / lrun[mt];
    #pragma unroll
    for (int r = 0; r < 4; ++r) {
      float iv = __shfl(inv, (l >> 4)*4 + r);
      int qg = q0 + mt*16 + lg*4 + r;
      #pragma unroll
      for (int dt = 0; dt < 2; ++dt)
        op[(size_t)qg*CDIM + dt*16 + lr] = (_Float16)(o[mt][dt][r] * iv);
    }
  }
}

// ---------------- K6: output projection via MFMA ----------------
// ao_h:[32768][192] fp16, pw:[192][192] fp16 -> out fp32 [32768][192]
__global__ __launch_bounds__(256) void k_proj(
    const _Float16* __restrict__ ao_h, const _Float16* __restrict__ pw,
    const float* __restrict__ pb, float* __restrict__ out) {
  int wid = threadIdx.x >> 6, l = threadIdx.x & 63;
  int lr = l & 15, lg = l >> 4;
  int m0 = blockIdx.x*128 + wid*32;
  int c0 = blockIdx.y*64;

  const f32x4 zero = {0.f,0.f,0.f,0.f};
  f32x4 acc[2][4];
  #pragma unroll
  for (int mt = 0; mt < 2; ++mt)
    #pragma unroll
    for (int nt = 0; nt < 4; ++nt) acc[mt][nt] = zero;

  for (int kc = 0; kc < 6; ++kc) {
    int ko = kc*32 + lg*8;
    f16x8 a0 = *(const f16x8*)(ao_h + (size_t)(m0 + lr)*192 + ko);
    f16x8 a1 = *(const f16x8*)(ao_h + (size_t)(m0 + 16 + lr)*192 + ko);
    #pragma unroll
    for (int nt = 0; nt < 4; ++nt) {
      f16x8 bf = *(const f16x8*)(pw + (size_t)(c0 + nt*16 + lr)*192 + ko);
      acc[0][nt] = __builtin_amdgcn_mfma_f32_16x16x32_f16(a0, bf, acc[0][nt], 0, 0, 0);
      acc[1][nt] = __builtin_amdgcn_mfma_f32_16x16x32_f16(a1, bf, acc[1][nt], 0, 0, 0);
    }
  }

  float bias[4];
  #pragma unroll
  for (int nt = 0; nt < 4; ++nt) bias[nt] = pb[c0 + nt*16 + lr];
  #pragma unroll
  for (int mt = 0; mt < 2; ++mt)
    #pragma unroll
    for (int r = 0; r < 4; ++r) {
      int m = m0 + mt*16 + lg*4 + r;
      #pragma unroll
      for (int nt = 0; nt < 4; ++nt)
        out[(size_t)m*CDIM + c0 + nt*16 + lr] = acc[mt][nt][r] + bias[nt];
    }
}

extern "C" void kernel_launch(void* const* d_in, const int* in_sizes, int n_in,
                              void* d_out, int out_size, void* d_ws, size_t ws_size,
                              hipStream_t stream) {
  const float* x           = (const float*)d_in[0];
  const float* mask        = (const float*)d_in[1];
  const float* qkv_w       = (const float*)d_in[2];
  const float* q_bias      = (const float*)d_in[3];
  const float* v_bias      = (const float*)d_in[4];
  const float* logit_scale = (const float*)d_in[5];
  const float* cpb_w1      = (const float*)d_in[6];
  const float* cpb_b1      = (const float*)d_in[7];
  const float* cpb_w2      = (const float*)d_in[8];
  const float* proj_w      = (const float*)d_in[9];
  const float* proj_b      = (const float*)d_in[10];
  const float* rel_table   = (const float*)d_in[11];
  const int*   rel_index   = (const int*)d_in[12];
  float* out = (float*)d_out;

  float* wsf = (float*)d_ws;
  float* tbl_t = wsf;                           // 6*3375 fp32, reserve 20480
  _Float16* hws = (_Float16*)(wsf + 20480);
  _Float16* qn  = hws;                          // 384*512*32 = 6291456
  _Float16* kn  = qn + 6291456;
  _Float16* vt  = kn + 6291456;                 // transposed V [pair][32][512]
  _Float16* bm  = vt + 6291456;                 // 96*1024*256 = 25165824 (50.3 MB)
  _Float16* wh  = bm + 25165824;                // 147456
  _Float16* xh  = wh + 147456;                  // 6291456; dead after k_qkv
  _Float16* ao_h = xh;                          // aliases xh (lifetimes disjoint)
  // total ~100.7 MB

  k_cpb<<<T3, 512, 0, stream>>>(rel_table, cpb_w1, cpb_b1, cpb_w2, tbl_t);
  k_bm<<<dim3(1024, 96), 64, 0, stream>>>(rel_index, tbl_t, mask, bm);
  k_xh<<<6144, 256, 0, stream>>>(x, xh);
  k_wh<<<144, 256, 0, stream>>>(qkv_w, proj_w, wh);
  k_qkv<<<dim3(256, 9), 256, 0, stream>>>(xh, wh, q_bias, v_bias, logit_scale, qn, kn, vt);
  k_attn<<<dim3(4, HEADS, B__), 256, 0, stream>>>(qn, kn, vt, bm, ao_h);
  k_proj<<<dim3(256, 3), 256, 0, stream>>>(ao_h, wh + 110592, proj_b, out);
}

// Round 6
// 249.260 us; speedup vs baseline: 1.1835x; 1.1835x over previous
//
#include <hip/hip_runtime.h>
#include <hip/hip_bf16.h>
#include <math.h>

#define B__ 64
#define NTOK 512
#define CDIM 192
#define HEADS 6
#define HD 32
#define NW 16
#define T3 3375
#define HID 512
#define LOG2E 1.4426950408889634f

typedef _Float16 f16x8 __attribute__((ext_vector_type(8)));
typedef _Float16 f16x4 __attribute__((ext_vector_type(4)));
typedef float    f32x4 __attribute__((ext_vector_type(4)));

#if __has_builtin(__builtin_amdgcn_exp2f)
#define EXP2F(x) __builtin_amdgcn_exp2f(x)
#else
#define EXP2F(x) __expf(0.69314718056f*(x))
#endif

// ---------------- K1: CPB MLP -> tbl_t[6][3375] (16*sigmoid applied) ----------------
__global__ __launch_bounds__(512) void k_cpb(
    const float* __restrict__ rel_table, const float* __restrict__ w1,
    const float* __restrict__ b1, const float* __restrict__ w2,
    float* __restrict__ tbl_t) {
  int i = blockIdx.x;          // table row 0..3374
  int t = threadIdx.x;         // hidden unit 0..511
  float t0 = rel_table[i*3+0], t1 = rel_table[i*3+1], t2 = rel_table[i*3+2];
  float hval = fmaxf(t0*w1[t*3+0] + t1*w1[t*3+1] + t2*w1[t*3+2] + b1[t], 0.f);
  __shared__ float red[8][6];
  int wv = t >> 6, lane = t & 63;
  #pragma unroll
  for (int hh = 0; hh < 6; ++hh) {
    float p = hval * w2[hh*HID + t];
    #pragma unroll
    for (int off = 32; off > 0; off >>= 1) p += __shfl_down(p, off);
    if (lane == 0) red[wv][hh] = p;
  }
  __syncthreads();
  if (t < 6) {
    float s = 0.f;
    #pragma unroll
    for (int w8 = 0; w8 < 8; ++w8) s += red[w8][t];
    tbl_t[t*T3 + i] = 16.f / (1.f + __expf(-s));
  }
}

// ---------------- K2a: bias*log2e -> swapped-S fragment layout, fp16 (3.1 MB) ----------
// Fragment element (lane l, reg r): k = kt*16 + (l>>4)*4 + r (C row), q = qt*16 + (l&15) (C col)
__global__ __launch_bounds__(64) void k_biasf(
    const int* __restrict__ idx, const float* __restrict__ tbl_t,
    _Float16* __restrict__ bias_f) {
  int bx = blockIdx.x;              // qt*32+kt
  int h  = blockIdx.y;
  int l  = threadIdx.x;
  int qt = bx >> 5, kt = bx & 31;
  int q  = qt*16 + (l & 15);
  int k0 = kt*16 + (l >> 4)*4;
  const int* ip = idx + (size_t)q*512 + k0;
  const float* tb = tbl_t + (size_t)h*T3;
  f16x4 v;
  #pragma unroll
  for (int r = 0; r < 4; ++r)
    v[r] = (_Float16)(LOG2E * tb[ip[r]]);
  *(f16x4*)(bias_f + ((size_t)(h*1024 + bx))*256 + l*4) = v;
}

// ---------------- K2b: mask*log2e -> swapped-S fragment layout, fp16 (8.4 MB) ----------
__global__ __launch_bounds__(64) void k_maskf(
    const float* __restrict__ mask, _Float16* __restrict__ mask_f) {
  int bx = blockIdx.x;
  int w  = blockIdx.y;
  int l  = threadIdx.x;
  int qt = bx >> 5, kt = bx & 31;
  int q  = qt*16 + (l & 15);
  int k0 = kt*16 + (l >> 4)*4;
  const float* mp = mask + (size_t)w*262144 + (size_t)q*512 + k0;
  f16x4 v;
  #pragma unroll
  for (int r = 0; r < 4; ++r)
    v[r] = (_Float16)(LOG2E * mp[r]);
  *(f16x4*)(mask_f + ((size_t)(w*1024 + bx))*256 + l*4) = v;
}

// ---------------- K3a: x fp32 -> fp16 ----------------
__global__ __launch_bounds__(256) void k_xh(
    const float* __restrict__ x, _Float16* __restrict__ xh) {
  int i = blockIdx.x*256 + threadIdx.x;     // 6144*256 = 1572864 float4 exactly
  float4 v = ((const float4*)x)[i];
  f16x4 h = {(_Float16)v.x, (_Float16)v.y, (_Float16)v.z, (_Float16)v.w};
  *(f16x4*)(xh + (size_t)i*4) = h;
}

// ---------------- K3b: weights fp32 -> fp16 (qkv_w then proj_w, contiguous) ----------------
__global__ __launch_bounds__(256) void k_wh(
    const float* __restrict__ qkv_w, const float* __restrict__ proj_w,
    _Float16* __restrict__ wh) {
  int i = blockIdx.x*256 + threadIdx.x;     // 144*256 = 36864 float4 exactly
  float4 v = (i < 27648) ? ((const float4*)qkv_w)[i] : ((const float4*)proj_w)[i - 27648];
  f16x4 h = {(_Float16)v.x, (_Float16)v.y, (_Float16)v.z, (_Float16)v.w};
  *(f16x4*)(wh + (size_t)i*4) = h;
}

// ---------------- K4: QKV GEMM via MFMA + bias + q/k row-norm + logit scale ----------------
// xh:[32768][192] fp16, wh(qkv):[576][192] fp16
// qn/kn: [B*H][N][HD] fp16 (qn pre-scaled by exp(ls)*log2e); v stored TRANSPOSED to vt[B*H][HD][N]
__global__ __launch_bounds__(256) void k_qkv(
    const _Float16* __restrict__ xh, const _Float16* __restrict__ wh,
    const float* __restrict__ q_bias, const float* __restrict__ v_bias,
    const float* __restrict__ logit_scale,
    _Float16* __restrict__ qn, _Float16* __restrict__ kn, _Float16* __restrict__ vt) {
  int wid = threadIdx.x >> 6, l = threadIdx.x & 63;
  int lr = l & 15, lg = l >> 4;
  int m0 = blockIdx.x*128 + wid*32;
  int cb = blockIdx.y;
  int c0 = cb*64;
  int p  = cb/3;                    // 0=q 1=k 2=v
  int pc0 = (cb - p*3)*64;          // col offset within part
  int h0 = pc0 >> 5;                // first head of this tile

  const f32x4 zero = {0.f,0.f,0.f,0.f};
  f32x4 acc[2][4];
  #pragma unroll
  for (int mt = 0; mt < 2; ++mt)
    #pragma unroll
    for (int nt = 0; nt < 4; ++nt) acc[mt][nt] = zero;

  const _Float16* wb = wh + (size_t)c0*192;
  for (int kc = 0; kc < 6; ++kc) {
    int ko = kc*32 + lg*8;
    f16x8 a0 = *(const f16x8*)(xh + (size_t)(m0 + lr)*192 + ko);
    f16x8 a1 = *(const f16x8*)(xh + (size_t)(m0 + 16 + lr)*192 + ko);
    #pragma unroll
    for (int nt = 0; nt < 4; ++nt) {
      f16x8 bf = *(const f16x8*)(wb + (size_t)(nt*16 + lr)*192 + ko);
      acc[0][nt] = __builtin_amdgcn_mfma_f32_16x16x32_f16(a0, bf, acc[0][nt], 0, 0, 0);
      acc[1][nt] = __builtin_amdgcn_mfma_f32_16x16x32_f16(a1, bf, acc[1][nt], 0, 0, 0);
    }
  }

  // epilogue: C row = m0 + mt*16 + lg*4 + r, col = nt*16 + lr
  if (p == 0) {
    float bq[4];
    #pragma unroll
    for (int nt = 0; nt < 4; ++nt) bq[nt] = q_bias[pc0 + nt*16 + lr];
    float s0 = __expf(fminf(logit_scale[h0], 4.6051702f)) * LOG2E;
    float s1 = __expf(fminf(logit_scale[h0+1], 4.6051702f)) * LOG2E;
    #pragma unroll
    for (int mt = 0; mt < 2; ++mt) {
      #pragma unroll
      for (int nt = 0; nt < 4; ++nt)
        #pragma unroll
        for (int r = 0; r < 4; ++r) acc[mt][nt][r] += bq[nt];
      #pragma unroll
      for (int r = 0; r < 4; ++r) {
        float ss0 = acc[mt][0][r]*acc[mt][0][r] + acc[mt][1][r]*acc[mt][1][r];
        float ss1 = acc[mt][2][r]*acc[mt][2][r] + acc[mt][3][r]*acc[mt][3][r];
        #pragma unroll
        for (int off = 1; off < 16; off <<= 1) {
          ss0 += __shfl_xor(ss0, off);
          ss1 += __shfl_xor(ss1, off);
        }
        float inv0 = s0 / fmaxf(sqrtf(ss0), 1e-12f);
        float inv1 = s1 / fmaxf(sqrtf(ss1), 1e-12f);
        int m = m0 + mt*16 + lg*4 + r;
        int b = m >> 9, n = m & 511;
        #pragma unroll
        for (int nt = 0; nt < 4; ++nt) {
          int h = h0 + (nt >> 1);
          int d = (nt & 1)*16 + lr;
          float val = acc[mt][nt][r] * ((nt < 2) ? inv0 : inv1);
          qn[(((size_t)b*HEADS + h)*NTOK + n)*HD + d] = (_Float16)val;
        }
      }
    }
  } else if (p == 1) {
    #pragma unroll
    for (int mt = 0; mt < 2; ++mt) {
      #pragma unroll
      for (int r = 0; r < 4; ++r) {
        float ss0 = acc[mt][0][r]*acc[mt][0][r] + acc[mt][1][r]*acc[mt][1][r];
        float ss1 = acc[mt][2][r]*acc[mt][2][r] + acc[mt][3][r]*acc[mt][3][r];
        #pragma unroll
        for (int off = 1; off < 16; off <<= 1) {
          ss0 += __shfl_xor(ss0, off);
          ss1 += __shfl_xor(ss1, off);
        }
        float inv0 = 1.f / fmaxf(sqrtf(ss0), 1e-12f);
        float inv1 = 1.f / fmaxf(sqrtf(ss1), 1e-12f);
        int m = m0 + mt*16 + lg*4 + r;
        int b = m >> 9, n = m & 511;
        #pragma unroll
        for (int nt = 0; nt < 4; ++nt) {
          int h = h0 + (nt >> 1);
          int d = (nt & 1)*16 + lr;
          float val = acc[mt][nt][r] * ((nt < 2) ? inv0 : inv1);
          kn[(((size_t)b*HEADS + h)*NTOK + n)*HD + d] = (_Float16)val;
        }
      }
    }
  } else {
    // V: store transposed vt[pair][d][n]; r indexes consecutive n -> packed f16x4 store
    float bv[4];
    #pragma unroll
    for (int nt = 0; nt < 4; ++nt) bv[nt] = v_bias[pc0 + nt*16 + lr];
    #pragma unroll
    for (int mt = 0; mt < 2; ++mt) {
      int m = m0 + mt*16 + lg*4;
      int b = m >> 9, n = m & 511;
      #pragma unroll
      for (int nt = 0; nt < 4; ++nt) {
        int h = h0 + (nt >> 1);
        int d = (nt & 1)*16 + lr;
        f16x4 hv;
        #pragma unroll
        for (int r = 0; r < 4; ++r) hv[r] = (_Float16)(acc[mt][nt][r] + bv[nt]);
        *(f16x4*)(vt + (((size_t)b*HEADS + h)*HD + d)*NTOK + n) = hv;
      }
    }
  }
}

// ---------------- K5: MFMA flash attention (swapped-S, split tables as MFMA C) -------
// flat grid 1536; XCD-grouped decode: each XCD runs 48 (b,h) pairs x 4 qblk contiguously
__global__ __launch_bounds__(256) void k_attn(
    const _Float16* __restrict__ qn, const _Float16* __restrict__ kn,
    const _Float16* __restrict__ vt, const _Float16* __restrict__ bias_f,
    const _Float16* __restrict__ mask_f, _Float16* __restrict__ ao_h) {
  __shared__ _Float16 plds[4][32][88];
  int bid = blockIdx.x;
  int xcd = bid & 7, slot = bid >> 3;     // dispatch round-robins bid%8 across XCDs
  int pr = xcd*48 + (slot >> 2);          // (b,h) pair 0..383, contiguous per XCD
  int qblk = slot & 3;
  int b = pr / 6, h = pr - 6*b;
  int w = b & (NW-1);
  int wid = threadIdx.x >> 6, l = threadIdx.x & 63;
  int lr = l & 15, lg = l >> 4;
  size_t pair = (size_t)b*HEADS + h;
  const _Float16* qb = qn + pair*NTOK*HD;
  const _Float16* kb = kn + pair*NTOK*HD;
  const _Float16* vb = vt + pair*HD*NTOK;
  const _Float16* bias_base = bias_f + (size_t)h*262144 + l*4;
  const _Float16* mask_base = mask_f + (size_t)w*262144 + l*4;
  int q0 = qblk*128 + wid*32;
  int qtb = q0 >> 4;

  // Q = B-operand fragment: lane lr = q-col, lg = d-octet
  f16x8 aq[2];
  aq[0] = *(const f16x8*)(qb + (size_t)(q0 + lr)*HD + lg*8);
  aq[1] = *(const f16x8*)(qb + (size_t)(q0 + 16 + lr)*HD + lg*8);

  const f32x4 zero = {0.f, 0.f, 0.f, 0.f};
  f32x4 o[2][2];
  o[0][0] = zero; o[0][1] = zero; o[1][0] = zero; o[1][1] = zero;
  float mrun[2] = {-1e30f, -1e30f};
  float lrun[2] = {0.f, 0.f};

  for (int ch = 0; ch < 8; ++ch) {
    // hoist all table fragments for this chunk: (bias+mask)*log2e, packed-f16 add
    f16x4 cfr[2][4];
    #pragma unroll
    for (int mt = 0; mt < 2; ++mt)
      #pragma unroll
      for (int kt = 0; kt < 4; ++kt) {
        size_t toff = ((size_t)((qtb + mt)*32 + ch*4 + kt))*256;
        f16x4 bf = *(const f16x4*)(bias_base + toff);
        f16x4 mf = *(const f16x4*)(mask_base + toff);
        cfr[mt][kt] = bf + mf;              // v_pk_add_f16
      }
    // K = A-operand fragments
    f16x8 bk[4];
    #pragma unroll
    for (int kt = 0; kt < 4; ++kt)
      bk[kt] = *(const f16x8*)(kb + (size_t)(ch*64 + kt*16 + lr)*HD + lg*8);
    // S^T = K Q + C   (C row=(lg,r)=k, col=lr=q)
    f32x4 s[2][4];
    #pragma unroll
    for (int mt = 0; mt < 2; ++mt) {
      #pragma unroll
      for (int kt = 0; kt < 4; ++kt) {
        f16x4 c4 = cfr[mt][kt];
        f32x4 cf = {(float)c4[0], (float)c4[1], (float)c4[2], (float)c4[3]};
        s[mt][kt] = __builtin_amdgcn_mfma_f32_16x16x32_f16(bk[kt], aq[mt], cf, 0, 0, 0);
      }
    }
    // online softmax in log2 domain; stats live at q = lr lanes
    #pragma unroll
    for (int mt = 0; mt < 2; ++mt) {
      float pm = s[mt][0][0];
      #pragma unroll
      for (int kt = 0; kt < 4; ++kt)
        #pragma unroll
        for (int r = 0; r < 4; ++r) pm = fmaxf(pm, s[mt][kt][r]);
      pm = fmaxf(pm, __shfl_xor(pm, 16));
      pm = fmaxf(pm, __shfl_xor(pm, 32));
      // defer-max (T13): skip rescale while tile max within 8 (log2) of running max
      if (!__all(pm <= mrun[mt] + 8.f)) {
        float mnew = fmaxf(mrun[mt], pm);
        float corr = EXP2F(mrun[mt] - mnew);
        lrun[mt] *= corr;
        mrun[mt] = mnew;
        // redistribute corr from lr-lanes to (lg,r)-lanes for O rescale
        #pragma unroll
        for (int r = 0; r < 4; ++r) {
          float cr = __shfl(corr, (l >> 4)*4 + r);
          o[mt][0][r] *= cr;
          o[mt][1][r] *= cr;
        }
      }
      float mref = mrun[mt];
      float rs = 0.f;
      #pragma unroll
      for (int kt = 0; kt < 4; ++kt) {
        f16x4 pv;
        #pragma unroll
        for (int r = 0; r < 4; ++r) {
          float p = EXP2F(s[mt][kt][r] - mref);
          pv[r] = (_Float16)p;
          rs += p;
        }
        *(f16x4*)(&plds[wid][mt*16 + lr][kt*16 + lg*4]) = pv;
      }
      rs += __shfl_xor(rs, 16);
      rs += __shfl_xor(rs, 32);
      lrun[mt] += rs;
    }
    // O += P V  (A=P rows=q, B=V cols=d; C row=(lg,r)=q, col=lr=d)
    #pragma unroll
    for (int kk = 0; kk < 2; ++kk) {
      f16x8 ap0 = *(const f16x8*)(&plds[wid][lr][kk*32 + lg*8]);
      f16x8 ap1 = *(const f16x8*)(&plds[wid][16 + lr][kk*32 + lg*8]);
      #pragma unroll
      for (int dt = 0; dt < 2; ++dt) {
        f16x8 bv = *(const f16x8*)(vb + (size_t)(dt*16 + lr)*NTOK + ch*64 + kk*32 + lg*8);
        o[0][dt] = __builtin_amdgcn_mfma_f32_16x16x32_f16(ap0, bv, o[0][dt], 0, 0, 0);
        o[1][dt] = __builtin_amdgcn_mfma_f32_16x16x32_f16(ap1, bv, o[1][dt], 0, 0, 0);
      }
    }
  }
  // epilogue: 1/l lives at lr-lanes; redistribute to (lg,r), store fp16
  _Float16* op = ao_h + (size_t)b*NTOK*CDIM + (size_t)h*HD;
  #pragma unroll
  for (int mt = 0; mt < 2; ++mt) {
    float inv = 1.f / lrun[mt];
    #pragma unroll
    for (int r = 0; r < 4; ++r) {
      float iv = __shfl(inv, (l >> 4)*4 + r);
      int qg = q0 + mt*16 + lg*4 + r;
      #pragma unroll
      for (int dt = 0; dt < 2; ++dt)
        op[(size_t)qg*CDIM + dt*16 + lr] = (_Float16)(o[mt][dt][r] * iv);
    }
  }
}

// ---------------- K6: output projection via MFMA ----------------
// ao_h:[32768][192] fp16, pw:[192][192] fp16 -> out fp32 [32768][192]
__global__ __launch_bounds__(256) void k_proj(
    const _Float16* __restrict__ ao_h, const _Float16* __restrict__ pw,
    const float* __restrict__ pb, float* __restrict__ out) {
  int wid = threadIdx.x >> 6, l = threadIdx.x & 63;
  int lr = l & 15, lg = l >> 4;
  int m0 = blockIdx.x*128 + wid*32;
  int c0 = blockIdx.y*64;

  const f32x4 zero = {0.f,0.f,0.f,0.f};
  f32x4 acc[2][4];
  #pragma unroll
  for (int mt = 0; mt < 2; ++mt)
    #pragma unroll
    for (int nt = 0; nt < 4; ++nt) acc[mt][nt] = zero;

  for (int kc = 0; kc < 6; ++kc) {
    int ko = kc*32 + lg*8;
    f16x8 a0 = *(const f16x8*)(ao_h + (size_t)(m0 + lr)*192 + ko);
    f16x8 a1 = *(const f16x8*)(ao_h + (size_t)(m0 + 16 + lr)*192 + ko);
    #pragma unroll
    for (int nt = 0; nt < 4; ++nt) {
      f16x8 bf = *(const f16x8*)(pw + (size_t)(c0 + nt*16 + lr)*192 + ko);
      acc[0][nt] = __builtin_amdgcn_mfma_f32_16x16x32_f16(a0, bf, acc[0][nt], 0, 0, 0);
      acc[1][nt] = __builtin_amdgcn_mfma_f32_16x16x32_f16(a1, bf, acc[1][nt], 0, 0, 0);
    }
  }

  float bias[4];
  #pragma unroll
  for (int nt = 0; nt < 4; ++nt) bias[nt] = pb[c0 + nt*16 + lr];
  #pragma unroll
  for (int mt = 0; mt < 2; ++mt)
    #pragma unroll
    for (int r = 0; r < 4; ++r) {
      int m = m0 + mt*16 + lg*4 + r;
      #pragma unroll
      for (int nt = 0; nt < 4; ++nt)
        out[(size_t)m*CDIM + c0 + nt*16 + lr] = acc[mt][nt][r] + bias[nt];
    }
}

extern "C" void kernel_launch(void* const* d_in, const int* in_sizes, int n_in,
                              void* d_out, int out_size, void* d_ws, size_t ws_size,
                              hipStream_t stream) {
  const float* x           = (const float*)d_in[0];
  const float* mask        = (const float*)d_in[1];
  const float* qkv_w       = (const float*)d_in[2];
  const float* q_bias      = (const float*)d_in[3];
  const float* v_bias      = (const float*)d_in[4];
  const float* logit_scale = (const float*)d_in[5];
  const float* cpb_w1      = (const float*)d_in[6];
  const float* cpb_b1      = (const float*)d_in[7];
  const float* cpb_w2      = (const float*)d_in[8];
  const float* proj_w      = (const float*)d_in[9];
  const float* proj_b      = (const float*)d_in[10];
  const float* rel_table   = (const float*)d_in[11];
  const int*   rel_index   = (const int*)d_in[12];
  float* out = (float*)d_out;

  float* wsf = (float*)d_ws;
  float* tbl_t = wsf;                           // 6*3375 fp32, reserve 20480
  _Float16* hws = (_Float16*)(wsf + 20480);
  _Float16* qn  = hws;                          // 384*512*32 = 6291456
  _Float16* kn  = qn + 6291456;
  _Float16* vt  = kn + 6291456;                 // transposed V [pair][32][512]
  _Float16* bias_f = vt + 6291456;              // 6*1024*256  = 1572864 (3.1 MB)
  _Float16* mask_f = bias_f + 1572864;          // 16*1024*256 = 4194304 (8.4 MB)
  _Float16* wh  = mask_f + 4194304;             // 147456
  _Float16* xh  = wh + 147456;                  // 6291456; dead after k_qkv
  _Float16* ao_h = xh;                          // aliases xh (lifetimes disjoint)
  // total ~62 MB

  k_cpb<<<T3, 512, 0, stream>>>(rel_table, cpb_w1, cpb_b1, cpb_w2, tbl_t);
  k_biasf<<<dim3(1024, HEADS), 64, 0, stream>>>(rel_index, tbl_t, bias_f);
  k_maskf<<<dim3(1024, NW), 64, 0, stream>>>(mask, mask_f);
  k_xh<<<6144, 256, 0, stream>>>(x, xh);
  k_wh<<<144, 256, 0, stream>>>(qkv_w, proj_w, wh);
  k_qkv<<<dim3(256, 9), 256, 0, stream>>>(xh, wh, q_bias, v_bias, logit_scale, qn, kn, vt);
  k_attn<<<1536, 256, 0, stream>>>(qn, kn, vt, bias_f, mask_f, ao_h);
  k_proj<<<dim3(256, 3), 256, 0, stream>>>(ao_h, wh + 110592, proj_b, out);
}